// Round 5
// baseline (170.316 us; speedup 1.0000x reference)
//
#include <hip/hip_runtime.h>
#include <hip/hip_fp16.h>
#include <hip/hip_cooperative_groups.h>
#include <math.h>

namespace cg = cooperative_groups;

// u_dot_v + sigmoid, D=64.
// R2:  fp16 table in d_ws, 8 lanes/edge.                              [89.7 us]
// R3/4: + 4 edges/8-lane group, 8 gathers in flight.                  [84.8 us]
// R5:  ws-free f32 diagnostic: dot 42.4 us (h is LLC-COLD each iter;
//      random 256B rows from HBM). Total 105.6.                      [105.6 us]
// R6:  16 gathers in flight: NULL vs R4 -> dot at line-rate floor.    [85.0 us]
//      Unified model: fixed harness overhead ~63 us (268MB ws poison fill
//      ~46 + reset restores + gaps); controllable = conv 4 + dot ~18.
// R7:  fuse conv+dot into ONE cooperative kernel (grid.sync between
//      phases): kills one launch boundary, overlaps index streaming with
//      conversion tail. 1024 blocks x 256 thr, __launch_bounds__(256,4)
//      guarantees 4 blocks/CU co-residency for grid.sync.
//      Predict total 85 -> 78-81; if null, declare roofline.

#define DOT_D 64

typedef int   v4i __attribute__((ext_vector_type(4)));
typedef float v4f __attribute__((ext_vector_type(4)));

__global__ __launch_bounds__(256, 4) void fused_conv_dot_kernel(
    const float* __restrict__ h,
    const int* __restrict__ src,
    const int* __restrict__ dst,
    float* __restrict__ out,
    __half* __restrict__ hh,
    int n8,     // ND/8: number of 8-float chunks in h
    int E)
{
    const int nthreads = gridDim.x * blockDim.x;
    const int tid = blockIdx.x * blockDim.x + threadIdx.x;

    // ---- Phase 1: f32 -> fp16 table (streaming; leaves table LLC/L2-hot) ----
    for (int i = tid; i < n8; i += nthreads) {
        float4 a = ((const float4*)h)[2 * i];
        float4 b = ((const float4*)h)[2 * i + 1];
        __half2 o[4];
        o[0] = __floats2half2_rn(a.x, a.y);
        o[1] = __floats2half2_rn(a.z, a.w);
        o[2] = __floats2half2_rn(b.x, b.y);
        o[3] = __floats2half2_rn(b.z, b.w);
        ((v4f*)hh)[i] = *(v4f*)o;   // 16 B store, cache-resident (NOT nontemporal)
    }

    cg::this_grid().sync();

    // ---- Phase 2: dot+sigmoid. 8 lanes/edge, 4 edges/group, grid-stride ----
    const int lane = tid & 7;
    const int g0   = tid >> 3;
    const int gstride = nthreads >> 3;
    const int ngroups = (E + 3) >> 2;

    for (int g = g0; g < ngroups; g += gstride) {
        int eb = g << 2;

        if (eb + 3 < E) {
            // Broadcast index loads: all 8 lanes read the same 16 B.
            v4i s4 = __builtin_nontemporal_load((const v4i*)(src + eb));
            v4i d4 = __builtin_nontemporal_load((const v4i*)(dst + eb));
            int ss[4] = { s4.x, s4.y, s4.z, s4.w };
            int dd[4] = { d4.x, d4.y, d4.z, d4.w };

            // 8 independent line-gathers in flight (16 B/lane = 1 line/row).
            float4 ur[4], vr[4];
#pragma unroll
            for (int i = 0; i < 4; ++i) {
                ur[i] = ((const float4*)(hh + (size_t)ss[i] * DOT_D))[lane];
                vr[i] = ((const float4*)(hh + (size_t)dd[i] * DOT_D))[lane];
            }

            v4f res;
#pragma unroll
            for (int i = 0; i < 4; ++i) {
                const __half2* up = (const __half2*)&ur[i];
                const __half2* vp = (const __half2*)&vr[i];
                float p = 0.0f;
#pragma unroll
                for (int k = 0; k < 4; ++k) {
                    float2 uf = __half22float2(up[k]);
                    float2 vf = __half22float2(vp[k]);
                    p = fmaf(uf.x, vf.x, p);
                    p = fmaf(uf.y, vf.y, p);
                }
                p += __shfl_xor(p, 4);
                p += __shfl_xor(p, 2);
                p += __shfl_xor(p, 1);
                res[i] = 1.0f / (1.0f + __expf(-p));
            }

            if (lane == 0) {
                __builtin_nontemporal_store(res, (v4f*)(out + eb));
            }
        } else {
            // Tail (E not divisible by 4).
            for (int i = 0; i < 4; ++i) {
                int e = eb + i;
                if (e >= E) break;
                int s = src[e];
                int d = dst[e];
                float4 ur = ((const float4*)(hh + (size_t)s * DOT_D))[lane];
                float4 vr = ((const float4*)(hh + (size_t)d * DOT_D))[lane];
                const __half2* up = (const __half2*)&ur;
                const __half2* vp = (const __half2*)&vr;
                float p = 0.0f;
#pragma unroll
                for (int k = 0; k < 4; ++k) {
                    float2 uf = __half22float2(up[k]);
                    float2 vf = __half22float2(vp[k]);
                    p = fmaf(uf.x, vf.x, p);
                    p = fmaf(uf.y, vf.y, p);
                }
                p += __shfl_xor(p, 4);
                p += __shfl_xor(p, 2);
                p += __shfl_xor(p, 1);
                if (lane == 0) out[e] = 1.0f / (1.0f + __expf(-p));
            }
        }
    }
}

// f32 fallback (ws-free) if d_ws is too small for the fp16 table.
__global__ __launch_bounds__(256) void dot_sigmoid_f32_kernel(
    const float* __restrict__ h,
    const int* __restrict__ src,
    const int* __restrict__ dst,
    float* __restrict__ out,
    int E)
{
    int tid  = blockIdx.x * blockDim.x + threadIdx.x;
    int lane = tid & 15;
    int e    = tid >> 4;
    if (e >= E) return;

    int s = src[e];
    int d = dst[e];
    float4 u = ((const float4*)(h + (size_t)s * DOT_D))[lane];
    float4 v = ((const float4*)(h + (size_t)d * DOT_D))[lane];
    float p = u.x * v.x + u.y * v.y + u.z * v.z + u.w * v.w;
    p += __shfl_xor(p, 8);
    p += __shfl_xor(p, 4);
    p += __shfl_xor(p, 2);
    p += __shfl_xor(p, 1);
    if (lane == 0) out[e] = 1.0f / (1.0f + __expf(-p));
}

extern "C" void kernel_launch(void* const* d_in, const int* in_sizes, int n_in,
                              void* d_out, int out_size, void* d_ws, size_t ws_size,
                              hipStream_t stream) {
    const float* h   = (const float*)d_in[0];
    const int*   src = (const int*)d_in[1];
    const int*   dst = (const int*)d_in[2];
    float*       out = (float*)d_out;

    int ND = in_sizes[0];          // N * 64
    int E  = in_sizes[1];
    size_t f16_bytes = (size_t)ND * sizeof(__half);

    if (ws_size >= f16_bytes) {
        __half* hh = (__half*)d_ws;
        int n8 = ND / 8;

        // 1024 blocks x 256 threads; __launch_bounds__(256,4) caps VGPR at
        // 128 -> 4 blocks/CU x 256 CUs co-resident, grid.sync() is safe.
        void* args[] = { (void*)&h, (void*)&src, (void*)&dst, (void*)&out,
                         (void*)&hh, (void*)&n8, (void*)&E };
        hipLaunchCooperativeKernel((void*)fused_conv_dot_kernel,
                                   dim3(1024), dim3(256), args, 0, stream);
    } else {
        long long total_threads = (long long)E * 16;
        int grid = (int)((total_threads + 255) / 256);
        dot_sigmoid_f32_kernel<<<grid, 256, 0, stream>>>(h, src, dst, out, E);
    }
}

// Round 6
// 84.187 us; speedup vs baseline: 2.0231x; 2.0231x over previous
//
#include <hip/hip_runtime.h>
#include <hip/hip_fp16.h>
#include <math.h>

// u_dot_v + sigmoid, D=64.
// R2:  fp16 table in d_ws, 8 lanes/edge.                              [89.7 us]
// R3/4: + 4 edges/8-lane group, 8 gathers in flight.                  [84.8 us]
// R5:  ws-free f32 diagnostic: dot 42.4 us cold/warm alike -> line-rate
//      bound (~76 G lines/s), not BW. Total 105.6.                   [105.6 us]
// R6:  16 gathers in flight: NULL -> dot at service-rate floor.       [85.0 us]
// R7:  cooperative conv+dot fusion: REGRESSION (94 us fused kernel;
//      1024-block cap halves waves/CU, serial grid-stride re-introduces
//      latency dependence). Reverted.                                [170.3 us]
// R8:  restore best verified config: R4 dot (4 edges/8-lane group) +
//      R6 wide conv. Model: ~63 us harness-fixed (268 MB ws-poison fill
//      ~46 us + restores), conv ~4, dot ~18 (1.6M lines @ ~89 G lines/s).
//      fp8/int8 rejected: absmax would be ~0.1 >> 0.0039.

#define DOT_D 64

typedef int   v4i __attribute__((ext_vector_type(4)));
typedef float v4f __attribute__((ext_vector_type(4)));

// f32 -> fp16 table: 8 floats in (2x float4), 16 B out per thread.
__global__ __launch_bounds__(256) void f32_to_f16_kernel(
    const float* __restrict__ h, __half2* __restrict__ hh, int n8)
{
    int i = blockIdx.x * blockDim.x + threadIdx.x;
    if (i >= n8) return;
    float4 a = ((const float4*)h)[2 * i];
    float4 b = ((const float4*)h)[2 * i + 1];
    __half2 o[4];
    o[0] = __floats2half2_rn(a.x, a.y);
    o[1] = __floats2half2_rn(a.z, a.w);
    o[2] = __floats2half2_rn(b.x, b.y);
    o[3] = __floats2half2_rn(b.z, b.w);
    ((v4f*)hh)[i] = *(v4f*)o;   // 16 B store, cache-resident
}

// 4 edges per 8-lane group; 8 independent 128 B-line gathers in flight.
__global__ __launch_bounds__(256) void dot_sigmoid_f16_mlp_kernel(
    const __half* __restrict__ h,
    const int* __restrict__ src,
    const int* __restrict__ dst,
    float* __restrict__ out,
    int E)
{
    int tid  = blockIdx.x * blockDim.x + threadIdx.x;
    int lane = tid & 7;     // 8 lanes per edge-group; 16 B/lane = 1 row line
    int g    = tid >> 3;    // group id: edges 4g .. 4g+3
    int eb   = g << 2;
    if (eb >= E) return;

    if (eb + 3 < E) {
        // Coalesced broadcast index loads: all 8 lanes read the same 16 B.
        v4i s4 = __builtin_nontemporal_load((const v4i*)(src + eb));
        v4i d4 = __builtin_nontemporal_load((const v4i*)(dst + eb));
        int ss[4] = { s4.x, s4.y, s4.z, s4.w };
        int dd[4] = { d4.x, d4.y, d4.z, d4.w };

        // Issue all 8 independent gathers (16 B/lane, one 128 B line/row).
        float4 ur[4], vr[4];
#pragma unroll
        for (int i = 0; i < 4; ++i) {
            ur[i] = ((const float4*)(h + (size_t)ss[i] * DOT_D))[lane];
            vr[i] = ((const float4*)(h + (size_t)dd[i] * DOT_D))[lane];
        }

        v4f res;
#pragma unroll
        for (int i = 0; i < 4; ++i) {
            const __half2* up = (const __half2*)&ur[i];
            const __half2* vp = (const __half2*)&vr[i];
            float p = 0.0f;
#pragma unroll
            for (int k = 0; k < 4; ++k) {
                float2 uf = __half22float2(up[k]);
                float2 vf = __half22float2(vp[k]);
                p = fmaf(uf.x, vf.x, p);
                p = fmaf(uf.y, vf.y, p);
            }
            p += __shfl_xor(p, 4);
            p += __shfl_xor(p, 2);
            p += __shfl_xor(p, 1);
            res[i] = 1.0f / (1.0f + __expf(-p));
        }

        if (lane == 0) {
            __builtin_nontemporal_store(res, (v4f*)(out + eb));
        }
    } else {
        // Tail: per-edge path (E not divisible by 4).
        for (int i = 0; i < 4; ++i) {
            int e = eb + i;
            if (e >= E) break;
            int s = src[e];
            int d = dst[e];
            float4 ur = ((const float4*)(h + (size_t)s * DOT_D))[lane];
            float4 vr = ((const float4*)(h + (size_t)d * DOT_D))[lane];
            const __half2* up = (const __half2*)&ur;
            const __half2* vp = (const __half2*)&vr;
            float p = 0.0f;
#pragma unroll
            for (int k = 0; k < 4; ++k) {
                float2 uf = __half22float2(up[k]);
                float2 vf = __half22float2(vp[k]);
                p = fmaf(uf.x, vf.x, p);
                p = fmaf(uf.y, vf.y, p);
            }
            p += __shfl_xor(p, 4);
            p += __shfl_xor(p, 2);
            p += __shfl_xor(p, 1);
            if (lane == 0) out[e] = 1.0f / (1.0f + __expf(-p));
        }
    }
}

// f32 fallback (ws-free) if d_ws is too small for the fp16 table.
__global__ __launch_bounds__(256) void dot_sigmoid_f32_kernel(
    const float* __restrict__ h,
    const int* __restrict__ src,
    const int* __restrict__ dst,
    float* __restrict__ out,
    int E)
{
    int tid  = blockIdx.x * blockDim.x + threadIdx.x;
    int lane = tid & 15;
    int e    = tid >> 4;
    if (e >= E) return;

    int s = src[e];
    int d = dst[e];
    float4 u = ((const float4*)(h + (size_t)s * DOT_D))[lane];
    float4 v = ((const float4*)(h + (size_t)d * DOT_D))[lane];
    float p = u.x * v.x + u.y * v.y + u.z * v.z + u.w * v.w;
    p += __shfl_xor(p, 8);
    p += __shfl_xor(p, 4);
    p += __shfl_xor(p, 2);
    p += __shfl_xor(p, 1);
    if (lane == 0) out[e] = 1.0f / (1.0f + __expf(-p));
}

extern "C" void kernel_launch(void* const* d_in, const int* in_sizes, int n_in,
                              void* d_out, int out_size, void* d_ws, size_t ws_size,
                              hipStream_t stream) {
    const float* h   = (const float*)d_in[0];
    const int*   src = (const int*)d_in[1];
    const int*   dst = (const int*)d_in[2];
    float*       out = (float*)d_out;

    int ND = in_sizes[0];          // N * 64
    int E  = in_sizes[1];
    size_t f16_bytes = (size_t)ND * sizeof(__half);

    if (ws_size >= f16_bytes) {
        __half* hh = (__half*)d_ws;
        int n8 = ND / 8;
        f32_to_f16_kernel<<<(n8 + 255) / 256, 256, 0, stream>>>(h, (__half2*)hh, n8);

        // 4 edges per 8-lane group -> (E+3)/4 groups, 8 threads each.
        long long groups = (E + 3) / 4;
        long long total_threads = groups * 8;
        int grid = (int)((total_threads + 255) / 256);
        dot_sigmoid_f16_mlp_kernel<<<grid, 256, 0, stream>>>(hh, src, dst, out, E);
    } else {
        long long total_threads = (long long)E * 16;
        int grid = (int)((total_threads + 255) / 256);
        dot_sigmoid_f32_kernel<<<grid, 256, 0, stream>>>(h, src, dst, out, E);
    }
}